// Round 21
// baseline (203.186 us; speedup 1.0000x reference)
//
#include <hip/hip_runtime.h>

#define HW 36864            // 192*192
#define HDIM 192
#define NUNITS 8192         // 1024 windows * 8 heads
#define QO 0
#define KO 768
#define VTO 1536
#define PO 0
// g-phase planes, pixel-major: wsP[((g*8+head)*HW + pix)*12 + dp] as u32 (h2).
#define P_BYTES (384ull * HW * 4)          // 56.6 MB

typedef __fp16 h2  __attribute__((ext_vector_type(2)));
typedef __fp16 v8h __attribute__((ext_vector_type(8)));
typedef float  v4f __attribute__((ext_vector_type(4)));

static __device__ __forceinline__ h2 pk2(float a, float b) {
    return __builtin_amdgcn_cvt_pkrtz(a, b);
}
static __device__ __forceinline__ unsigned h2u(h2 x) {
    union { h2 h; unsigned u; } c; c.h = x; return c.u;
}
static __device__ __forceinline__ h2 u2h(unsigned x) {
    union { unsigned u; h2 h; } c; c.u = x; return c.h;
}
static __device__ __forceinline__ v8h as_v8h(uint4 u) {
    union { uint4 u; v8h h; } c; c.u = u; return c.h;
}

// One wave per block. LDS = 2688 dw frag region (raw gather overlays [0,2304))
// + frs/fis = 11264 B exactly -> 14 blocks/CU (was 19.5KB -> 8). Two-phase
// 36-channel cooperative gather; per-wave LDS ops are in-order so the
// overwrite-after-pull is safe (fences stop compiler reordering only).
__global__ __launch_bounds__(64, 3)
void attn_mfma(const float* __restrict__ x,
               const float* __restrict__ fc,
               const float* __restrict__ wgt,
               float* __restrict__ out,        // used only in atomic fallback
               unsigned* __restrict__ wsP)     // may be null -> atomic fallback
{
    __shared__ unsigned lds[2688];
    __shared__ float frs[64], fis[64];

    const int lane = threadIdx.x;
    const int gid  = blockIdx.x;
    const int head = gid & 7;
    const int wi   = gid >> 3;
    const int g    = wi & 3;
    const int iw   = (wi >> 2) & 15;
    const int ih   = wi >> 6;

    unsigned* uld = lds;

    {
        float2 t = ((const float2*)fc)[lane];
        frs[lane] = t.x; fis[lane] = t.y;
    }
    __syncthreads();   // single wave: near-free; orders frs/fis

    // ---- phase 1: cooperative gather + PE + stage ----
    const int r = lane >> 3, col = lane & 7;
    const int h0 = ih * 12 + r, w0 = iw * 12 + col;
    int in_h = h0 + ((g & 1) ? 6 : 0); if (in_h >= HDIM) in_h = 2 * HDIM - 2 - in_h;
    int in_w = w0 + ((g & 2) ? 6 : 0); if (in_w >= HDIM) in_w = 2 * HDIM - 2 - in_w;

    float q[24], k[24], v[24];
    const bool wrefl = (g & 2) && (iw == 15);   // w-reflection breaks 16B spans (~3%)
    if (!wrefl) {
        // lane -> (ch4 = lane>>4: 4 channel-groups, row = (lane&15)>>1, half = lane&1)
        const int ch4  = lane >> 4;
        const int row  = (lane & 15) >> 1;
        const int half = lane & 1;
        int rh = ih * 12 + row + ((g & 1) ? 6 : 0);
        if (rh >= HDIM) rh = 2 * HDIM - 2 - rh;          // per-row h-reflection ok
        const int wb = iw * 12 + ((g & 2) ? 6 : 0);       // no w-reflection on fast path
        const size_t rowoff = (size_t)rh * HDIM + wb + half * 4;

        uint4 gA[9], gB[9];
#pragma unroll
        for (int i = 0; i < 9; ++i) {                     // phase A: c = 0..35
            const int c = i * 4 + ch4;
            const int qkv = c / 24, dd = c - qkv * 24;
            gA[i] = *(const uint4*)(x + (size_t)(qkv * 192 + head * 24 + dd) * HW + rowoff);
        }
#pragma unroll
        for (int i = 0; i < 9; ++i) {                     // phase B: c = 36..71
            const int c = 36 + i * 4 + ch4;
            const int qkv = c / 24, dd = c - qkv * 24;
            gB[i] = *(const uint4*)(x + (size_t)(qkv * 192 + head * 24 + dd) * HW + rowoff);
        }
        unsigned* dst0 = &lds[ch4 * 64 + row * 8 + half * 4];
#pragma unroll
        for (int i = 0; i < 9; ++i)                       // write A (vmcnt waits gA only)
            *(uint4*)(dst0 + (size_t)i * 256) = gA[i];
        asm volatile("" ::: "memory");
        const float* Rf = (const float*)lds;              // pull A: q, k[0..12)
#pragma unroll
        for (int dd = 0; dd < 24; ++dd) q[dd] = Rf[dd * 64 + lane];
#pragma unroll
        for (int dd = 0; dd < 12; ++dd) k[dd] = Rf[(24 + dd) * 64 + lane];
        asm volatile("" ::: "memory");
#pragma unroll
        for (int i = 0; i < 9; ++i)                       // write B (overwrite; in-order)
            *(uint4*)(dst0 + (size_t)i * 256) = gB[i];
        asm volatile("" ::: "memory");
#pragma unroll
        for (int dd = 12; dd < 24; ++dd) k[dd] = Rf[(dd - 12) * 64 + lane];
#pragma unroll
        for (int dd = 0; dd < 24; ++dd) v[dd] = Rf[(12 + dd) * 64 + lane];
    } else {
        const float* xb = x + (size_t)(head * 24) * HW + in_h * HDIM + in_w;
#pragma unroll
        for (int dd = 0; dd < 24; ++dd) q[dd] = xb[(size_t)dd * HW];
#pragma unroll
        for (int dd = 0; dd < 24; ++dd) k[dd] = xb[(size_t)dd * HW + (size_t)192 * HW];
#pragma unroll
        for (int dd = 0; dd < 24; ++dd) v[dd] = xb[(size_t)dd * HW + (size_t)384 * HW];
    }

#pragma unroll
    for (int p = 0; p < 8; ++p) {
        const float frr = frs[r * 8 + p],   fir = fis[r * 8 + p];
        const float frc = frs[col * 8 + p], fic = fis[col * 8 + p];
        {
            float a = q[3*p], b = q[3*p+1], c3 = q[3*p+2];
            float b2 = a * fir + b * frr;
            q[3*p]   = a * frr - b * fir;
            q[3*p+1] = b2 * frc - c3 * fic;
            q[3*p+2] = b2 * fic + c3 * frc;
        }
        {
            float a = k[3*p], b = k[3*p+1], c3 = k[3*p+2];
            float b2 = a * fir + b * frr;
            k[3*p]   = a * frr - b * fir;
            k[3*p+1] = b2 * frc - c3 * fic;
            k[3*p+2] = b2 * fic + c3 * frc;
        }
    }

    // raw region fully consumed into regs above; staging may overwrite it
    asm volatile("" ::: "memory");
    {
        // log2(e)/sqrt(24): folds the exp->exp2 conversion into the Q scale
        const float sc = 0.29448903f;
        uint2* qw = (uint2*)&uld[QO + lane * 12];
        uint2* kw = (uint2*)&uld[KO + lane * 12];
#pragma unroll
        for (int j = 0; j < 3; ++j) {
            qw[2*j]   = make_uint2(h2u(pk2(q[8*j]*sc,   q[8*j+1]*sc)),
                                   h2u(pk2(q[8*j+2]*sc, q[8*j+3]*sc)));
            qw[2*j+1] = make_uint2(h2u(pk2(q[8*j+4]*sc, q[8*j+5]*sc)),
                                   h2u(pk2(q[8*j+6]*sc, q[8*j+7]*sc)));
            kw[2*j]   = make_uint2(h2u(pk2(k[8*j],   k[8*j+1])),
                                   h2u(pk2(k[8*j+2], k[8*j+3])));
            kw[2*j+1] = make_uint2(h2u(pk2(k[8*j+4], k[8*j+5])),
                                   h2u(pk2(k[8*j+6], k[8*j+7])));
        }
    }
    {
#pragma unroll
        for (int i = 0; i < 5; ++i) {           // zero V^T rows 24..31 (dw 2400..2687)
            int idx = lane + i * 64;
            if (idx < 288) uld[VTO + 24 * 36 + idx] = 0;
        }
        __fp16* vt = (__fp16*)&uld[VTO];
        vt[24 * 72 + lane] = (__fp16)1.0f;      // ones row (row 24) -> denominators
#pragma unroll
        for (int dd = 0; dd < 24; ++dd) vt[dd * 72 + lane] = (__fp16)v[dd];
    }
    asm volatile("" ::: "memory");

    // ---- phase 2 ----
    const int qq = lane >> 4, l15 = lane & 15;
    // zero source for qq==3 fragment slots: VT row 25 (dw 2436..2471) — zeroed
    // above and NEVER overwritten (row 24 holds the ones; P stops at dw 2303).
    // R18 BUG: pointed at row 24 (ones) -> +8 on every logit -> f16 overflow.
    const unsigned* zsrc = &uld[VTO + 25 * 36];
    v8h Qf[4], Kf[4];
#pragma unroll
    for (int t = 0; t < 4; ++t) {
        const unsigned* qa = (qq < 3) ? &uld[QO + (16*t + l15)*12 + 4*qq] : zsrc;
        const unsigned* ka = (qq < 3) ? &uld[KO + (16*t + l15)*12 + 4*qq] : zsrc;
        Qf[t] = as_v8h(*(const uint4*)qa);
        Kf[t] = as_v8h(*(const uint4*)ka);
    }
    v8h Vf[2][2];
#pragma unroll
    for (int dt = 0; dt < 2; ++dt)
#pragma unroll
        for (int ks = 0; ks < 2; ++ks)
            Vf[dt][ks] = as_v8h(*(const uint4*)&uld[VTO + (16*dt + l15)*36 + 16*ks + 4*qq]);

    // Swapped-operand QK^T: mfma(K,Q) gives S^T -> pack exp2'd P pairs,
    // one ds_write_b64 per tile.
#pragma unroll
    for (int tn = 0; tn < 4; ++tn) {
#pragma unroll
        for (int tm = 0; tm < 4; ++tm) {
            v4f c = {0.f, 0.f, 0.f, 0.f};
            c = __builtin_amdgcn_mfma_f32_16x16x32_f16(Kf[tn], Qf[tm], c, 0, 0, 0);
            uint2 w = make_uint2(h2u(pk2(__builtin_amdgcn_exp2f(c[0]),
                                         __builtin_amdgcn_exp2f(c[1]))),
                                 h2u(pk2(__builtin_amdgcn_exp2f(c[2]),
                                         __builtin_amdgcn_exp2f(c[3]))));
            *(uint2*)&uld[PO + (16*tm + l15)*36 + 8*tn + 2*qq] = w;
        }
    }

    v4f O[2][4];
#pragma unroll
    for (int dt = 0; dt < 2; ++dt)
#pragma unroll
        for (int lt = 0; lt < 4; ++lt)
            O[dt][lt] = (v4f){0.f, 0.f, 0.f, 0.f};
#pragma unroll
    for (int lt = 0; lt < 4; ++lt) {
#pragma unroll
        for (int ks = 0; ks < 2; ++ks) {
            v8h Pf = as_v8h(*(const uint4*)&uld[PO + (16*lt + l15)*36 + 16*ks + 4*qq]);
            O[0][lt] = __builtin_amdgcn_mfma_f32_16x16x32_f16(Vf[0][ks], Pf, O[0][lt], 0, 0, 0);
            O[1][lt] = __builtin_amdgcn_mfma_f32_16x16x32_f16(Vf[1][ks], Pf, O[1][lt], 0, 0, 0);
        }
    }

    float inv[4];
#pragma unroll
    for (int lt = 0; lt < 4; ++lt)
        inv[lt] = 1.0f / __shfl(O[1][lt][0], 32 + l15, 64);

    if (wsP) {
        // Pixel-major epilogue (R15/R17-verified): LDS-stage sm[pixel][dp],
        // then lane = pixel writes 48B (3x uint4) -> 384B row-runs.
        unsigned* sm = uld;
        asm volatile("" ::: "memory");
#pragma unroll
        for (int lt = 0; lt < 4; ++lt) {
            const int   l  = 16*lt + l15;
            const float sc = inv[lt];
            sm[l*12 + 2*qq]     = h2u(pk2(O[0][lt][0]*sc, O[0][lt][1]*sc));
            sm[l*12 + 2*qq + 1] = h2u(pk2(O[0][lt][2]*sc, O[0][lt][3]*sc));
            if (qq < 2) {
                sm[l*12 + 8 + 2*qq] = h2u(pk2(O[1][lt][0]*sc, O[1][lt][1]*sc));
                sm[l*12 + 9 + 2*qq] = h2u(pk2(O[1][lt][2]*sc, O[1][lt][3]*sc));
            }
        }
        asm volatile("" ::: "memory");
        const int goffh = (g & 1) ? 6 : 0, goffw = (g & 2) ? 6 : 0;
        const int oh = ih * 12 + (lane >> 3) + goffh;
        const int ow = iw * 12 + (lane & 7)  + goffw;
        if (oh < HDIM && ow < HDIM) {
            uint4* dst = (uint4*)&wsP[((size_t)(g * 8 + head) * HW
                                       + (size_t)oh * HDIM + ow) * 12];
            const uint4* src = (const uint4*)&sm[lane * 12];
            dst[0] = src[0]; dst[1] = src[1]; dst[2] = src[2];
        }
    } else {
        // atomic fallback
#pragma unroll
        for (int lt = 0; lt < 4; ++lt) {
            const int l  = 16*lt + l15;
            const int oh = ih * 12 + (l >> 3) + ((g & 1) ? 6 : 0);
            const int ow = iw * 12 + (l & 7)  + ((g & 2) ? 6 : 0);
            if (oh < HDIM && ow < HDIM) {
                const float sc = inv[lt] / wgt[oh * HDIM + ow];
                float* ob = out + (size_t)(head * 24) * HW + oh * HDIM + ow;
#pragma unroll
                for (int rg = 0; rg < 4; ++rg)
                    atomicAdd(ob + (size_t)(4*qq + rg) * HW, O[0][lt][rg] * sc);
                if (qq < 2) {
#pragma unroll
                    for (int rg = 0; rg < 4; ++rg)
                        atomicAdd(ob + (size_t)(16 + 4*qq + rg) * HW, O[1][lt][rg] * sc);
                }
            }
        }
    }
}

// ---- phase B: overlap-add merge (R15/R17-verified). Thread = (head, pixel). ----
__global__ __launch_bounds__(256)
void merge_out(const unsigned* __restrict__ wsP,
               const float* __restrict__ wgt,
               float* __restrict__ out)
{
    const int idx  = blockIdx.x * 256 + threadIdx.x;   // grid exact: 8*HW
    const int head = idx / HW;
    const int pix  = idx - head * HW;
    const int h    = pix / HDIM;
    const int w    = pix - h * HDIM;

    float acc[24];
#pragma unroll
    for (int d = 0; d < 24; ++d) acc[d] = 0.f;

#pragma unroll
    for (int g = 0; g < 4; ++g) {
        const int hh = h - ((g & 1) ? 6 : 0);
        const int ww = w - ((g & 2) ? 6 : 0);
        if (hh < 0 || ww < 0) continue;
        if (hh % 12 >= 8 || ww % 12 >= 8) continue;
        const uint4* src = (const uint4*)&wsP[((size_t)(g * 8 + head) * HW + pix) * 12];
#pragma unroll
        for (int j = 0; j < 3; ++j) {
            const uint4 u = src[j];
#pragma unroll
            for (int t = 0; t < 4; ++t) {
                const h2 p = u2h(((const unsigned*)&u)[t]);
                acc[8*j + 2*t]     += (float)p[0];
                acc[8*j + 2*t + 1] += (float)p[1];
            }
        }
    }
    const float wv = wgt[pix];
#pragma unroll
    for (int d = 0; d < 24; ++d)
        out[(size_t)(head * 24 + d) * HW + pix] = acc[d] / wv;
}

extern "C" void kernel_launch(void* const* d_in, const int* in_sizes, int n_in,
                              void* d_out, int out_size, void* d_ws, size_t ws_size,
                              hipStream_t stream) {
    const float* x   = (const float*)d_in[0];
    const float* fc  = (const float*)d_in[1];
    const float* wgt = (const float*)d_in[2];
    float* out = (float*)d_out;

    unsigned* wsP = ws_size >= P_BYTES ? (unsigned*)d_ws : nullptr;

    if (!wsP)
        (void)hipMemsetAsync(out, 0, (size_t)out_size * sizeof(float), stream);
    attn_mfma<<<NUNITS, 64, 0, stream>>>(x, fc, wgt, out, wsP);
    if (wsP)
        merge_out<<<8 * HW / 256, 256, 0, stream>>>(wsP, wgt, out);
}